// Round 13
// baseline (89.048 us; speedup 1.0000x reference)
//
#include <hip/hip_runtime.h>

typedef __bf16 bf16;
typedef __bf16 bf16x8 __attribute__((ext_vector_type(8)));
typedef __bf16 bf16x4 __attribute__((ext_vector_type(4)));
typedef __bf16 bf16x2 __attribute__((ext_vector_type(2)));
typedef float  f32x4  __attribute__((ext_vector_type(4)));
typedef float  f32x16 __attribute__((ext_vector_type(16)));
typedef unsigned int uint32;

constexpr int DIM_  = 1024;
constexpr int NH    = 16;
constexpr int CHD   = 32;     // current head dim
constexpr int CDIM  = 512;    // NH * CHD
constexpr int CQ    = 1536;   // 3 * CDIM
constexpr int NSEQ  = 2048;
constexpr int M_    = 4096;   // B * N
constexpr float ATT_SCALE = 0.17677669529663687f; // (64^-0.5)/sqrt(0.5)
constexpr float QS_LOG2 = ATT_SCALE * 1.4426950408889634f; // fold log2(e): softmax in exp2 domain

__device__ inline void gload16(const bf16* g, bf16* l) {
    __builtin_amdgcn_global_load_lds((const __attribute__((address_space(1))) void*)g,
                                     (__attribute__((address_space(3))) void*)l, 16, 0, 0);
}

// ---------------- fused cast: x, w_qkv, w_proj slice -> bf16 (one launch) ----------------
constexpr int NX4 = M_ * DIM_ / 4;        // 1048576
constexpr int NW4 = CQ * DIM_ / 4;        // 393216
constexpr int NP4 = DIM_ * (CDIM / 4);    // 131072
__global__ void cast_fused(const float* __restrict__ x, const float* __restrict__ wq,
                           const float* __restrict__ wp, bf16* __restrict__ xb,
                           bf16* __restrict__ wqb, bf16* __restrict__ wpb) {
    int i = blockIdx.x * blockDim.x + threadIdx.x;   // exactly NX4+NW4+NP4 threads
    const float4* src;
    bf16x4* dst;
    if (i < NX4) {
        src = reinterpret_cast<const float4*>(x) + i;
        dst = reinterpret_cast<bf16x4*>(xb) + i;
    } else if (i < NX4 + NW4) {
        int j = i - NX4;
        src = reinterpret_cast<const float4*>(wq) + j;
        dst = reinterpret_cast<bf16x4*>(wqb) + j;
    } else {
        int j = i - (NX4 + NW4);
        int c = j >> 7, j4 = j & 127;
        src = reinterpret_cast<const float4*>(wp + c * DIM_) + j4;
        dst = reinterpret_cast<bf16x4*>(wpb + c * CDIM) + j4;
    }
    float4 v = *src;
    bf16x4 o = { (bf16)v.x, (bf16)v.y, (bf16)v.z, (bf16)v.w };
    *dst = o;
}

// ---------------- NT GEMM: C[m][n] = sum_k A[m][k] * B[n][k] ----------------
// 128x64 tile, 4 waves (2x2), wave tile 64x32, BK=32. 3-deep LDS ring, one barrier
// per K-step, counted vmcnt. A/B staged as 16x32 FRAG-BLOBS (per-lane pre-swizzled
// global src, linear LDS dest) so every ds_read is base+lane*16: conflict-free.
// MODE 1: qkv epilogue -> q/k via LDS-bounce (vector stores, q pre-scaled), v transposed
// MODE 2: proj epilogue -> f32 out + bias
template<int KDIM, int MODE>
__launch_bounds__(256)
__global__ void gemm_nt(const bf16* __restrict__ A, const bf16* __restrict__ Bm,
                        bf16* __restrict__ qbo, bf16* __restrict__ kbo, bf16* __restrict__ vto,
                        float* __restrict__ Cf, const float* __restrict__ bias) {
    __shared__ __align__(16) bf16 SMEM[18432];   // As ring 12288 | Bs ring 6144; bounce reuse
    bf16* As = SMEM;             // 3 bufs x 4096 elems (8 blobs of 16x32)
    bf16* Bs = SMEM + 12288;     // 3 bufs x 2048 elems (4 blobs)
    const int tid = threadIdx.x;
    const int w = tid >> 6, lane = tid & 63;
    const int m0 = blockIdx.x * 128, n0 = blockIdx.y * 64;
    const int wr = (w >> 1) * 64, wc = (w & 1) * 32;
    const int cl = lane & 15, gk8 = (lane >> 4) * 8;

    // blob-staging source: lane -> row (blob*16 + cl), k-col gk8
    const bf16* gaA = A  + (m0 + cl) * KDIM + gk8;
    const bf16* gbB = Bm + (n0 + cl) * KDIM + gk8;

    constexpr int KT = KDIM / 32;

    auto stage = [&](int kt, int b) {
        gload16(gaA + (2 * w    ) * 16 * KDIM + kt * 32, As + b * 4096 + (2 * w    ) * 512);
        gload16(gaA + (2 * w + 1) * 16 * KDIM + kt * 32, As + b * 4096 + (2 * w + 1) * 512);
        gload16(gbB + w * 16 * KDIM + kt * 32,           Bs + b * 2048 + w * 512);
    };
    stage(0, 0);
    stage(1, 1);

    f32x4 acc[4][2] = {};

    for (int kt = 0; kt < KT; ++kt) {
        if (kt < KT - 1) asm volatile("s_waitcnt vmcnt(3)" ::: "memory");
        else             asm volatile("s_waitcnt vmcnt(0)" ::: "memory");
        __builtin_amdgcn_s_barrier();
        __builtin_amdgcn_sched_barrier(0);
        if (kt + 2 < KT) stage(kt + 2, (kt + 2) % 3);

        const bf16* as = As + (kt % 3) * 4096 + (w >> 1) * 2048;   // this wave's 4 A-blobs
        const bf16* bs = Bs + (kt % 3) * 2048 + (w & 1) * 1024;    // this wave's 2 B-blobs
        bf16x8 af[4], bfr[2];
#pragma unroll
        for (int i = 0; i < 4; ++i)
            af[i]  = *reinterpret_cast<const bf16x8*>(as + i * 512 + lane * 8);
#pragma unroll
        for (int j = 0; j < 2; ++j)
            bfr[j] = *reinterpret_cast<const bf16x8*>(bs + j * 512 + lane * 8);
#pragma unroll
        for (int i = 0; i < 4; ++i)
#pragma unroll
            for (int j = 0; j < 2; ++j)
                acc[i][j] = __builtin_amdgcn_mfma_f32_16x16x32_bf16(af[i], bfr[j], acc[i][j], 0, 0, 0);
    }

    const int rg = (lane >> 4) * 4;   // D layout: row=(l>>4)*4+r, col=l&15
    if constexpr (MODE == 2) {
#pragma unroll
        for (int i = 0; i < 4; ++i)
#pragma unroll
            for (int j = 0; j < 2; ++j) {
                const int row = m0 + wr + i * 16 + rg;
                const int col = n0 + wc + j * 16 + cl;
                const float bv = bias[col];
#pragma unroll
                for (int r = 0; r < 4; ++r)
                    Cf[(row + r) * DIM_ + col] = acc[i][j][r] + bv;
            }
    } else {
        const int sec = n0 >> 9;   // block-uniform: 0=q 1=k 2=v
        if (sec == 2) {
#pragma unroll
            for (int i = 0; i < 4; ++i)
#pragma unroll
                for (int j = 0; j < 2; ++j) {
                    const int row = m0 + wr + i * 16 + rg;
                    const int col = n0 + wc + j * 16 + cl;
                    const int rem = col & 511;
                    const int h = rem >> 5, d = rem & 31;
                    const int bb = row >> 11, pos = row & 2047;
                    const int bh = bb * NH + h;
                    bf16x4 st;
#pragma unroll
                    for (int r = 0; r < 4; ++r) st[r] = (bf16)acc[i][j][r];
                    *reinterpret_cast<bf16x4*>(vto + (bh * CHD + d) * NSEQ + pos) = st;
                }
        } else {
            // bounce through LDS -> coalesced b128 stores
            const float sc = sec ? 1.0f : QS_LOG2;
            __syncthreads();   // done reading As/Bs
#pragma unroll
            for (int i = 0; i < 4; ++i)
#pragma unroll
                for (int j = 0; j < 2; ++j)
#pragma unroll
                    for (int r = 0; r < 4; ++r)
                        SMEM[(wr + i * 16 + rg + r) * 72 + wc + j * 16 + cl] =
                            (bf16)(acc[i][j][r] * sc);
            __syncthreads();
            const int row = tid >> 1, ch = (tid & 1) * 32;
            const int m = m0 + row, bb = m >> 11, pos = m & 2047;
            const int col0 = n0 + ch;
            const int h = (col0 & 511) >> 5;
            bf16* dst = (sec ? kbo : qbo) + ((bb * NH + h) * NSEQ + pos) * CHD;
#pragma unroll
            for (int v4 = 0; v4 < 4; ++v4)
                *reinterpret_cast<bf16x8*>(dst + v4 * 8) =
                    *reinterpret_cast<const bf16x8*>(SMEM + row * 72 + ch + v4 * 8);
        }
    }
}

// pack two f32 -> dword of two bf16 (v_cvt_pk_bf16_f32)
__device__ inline uint32 pkbf(float lo, float hi) {
    bf16x2 t = { (bf16)lo, (bf16)hi };
    return __builtin_bit_cast(uint32, t);
}

// ---------------- flash attention v9: 16-wave blocks, kv-quarters, 8 waves/SIMD ----------------
// Grid 512 blocks x 1024 thr (16 waves): strip p = w&3 (32 q-rows each), kv-quarter
// qt = w>>2 (512 kv each). Per wave: 8 KV tiles of 64, two 32-kv h-blocks per tile:
// QK(2 MFMA, swapped) -> p=exp2(s) (bare v_exp_f32, zero-shift softmax) -> permlane
// pack -> PV (one accumulator). K/V double-buffered per quarter in LDS (64KB total)
// via global_load_lds frag-blobs. Occupancy: 2 blocks/CU exact = 8 waves/SIMD (VGPR
// must stay <=64 -> launch_bounds(1024,8)). 4-way quarter merge via LDS at the end.
__launch_bounds__(1024, 8)
__global__ void flash_kernel(const bf16* __restrict__ qb, const bf16* __restrict__ kb,
                             const bf16* __restrict__ vt, bf16* __restrict__ outb) {
    __shared__ __align__(16) char smem[65536];  // [quarter][par][K 4KB | V 4KB]; merge reuse
    const int tid = threadIdx.x;
    const int w = tid >> 6, lane = tid & 63;
    const int lq = lane & 31, hi = lane >> 5;
    const int p = w & 3, qt = w >> 2;

    const int blin = blockIdx.x;                 // XCD swizzle: 4 heads per XCD
    const int xcd = blin & 7, within = blin >> 3;
    const int head = xcd * 4 + (within >> 4);
    const int qblk = within & 15;
    const int q0 = qblk * 128 + p * 32;

    const bf16* Q = qb + head * (NSEQ * CHD);
    const bf16* K = kb + head * (NSEQ * CHD);
    const bf16* V = vt + head * (CHD * NSEQ);    // V^T: [d][pos]

    // Q B-fragments (kc=0,1): lane -> Q[q0+lq][16*kc + 8*hi + j]
    const bf16x8 qf0 = *reinterpret_cast<const bf16x8*>(Q + (q0 + lq) * CHD + hi * 8);
    const bf16x8 qf1 = *reinterpret_cast<const bf16x8*>(Q + (q0 + lq) * CHD + 16 + hi * 8);

    char* base = smem + qt * 16384;
    const int kvbeg = qt * 512;                  // this quarter's kv range
    // staging: strip-wave p stages K-blob p (sh=p>>1, skc=p&1) and V-blob p of its quarter
    const int sh = p >> 1, skc = p & 1;
    const bf16* srcK = K + (kvbeg + sh * 32 + lq) * CHD + skc * 16 + hi * 8;
    const bf16* srcV = V + lq * NSEQ + kvbeg + p * 16 + hi * 8;

    auto stage = [&](int t) {
        char* b = base + (t & 1) * 8192;
        gload16(srcK + t * 64 * CHD, (bf16*)(b + p * 1024));
        gload16(srcV + t * 64,       (bf16*)(b + 4096 + p * 1024));
    };
    stage(0);
    __syncthreads();

    f32x16 o = {};
    float rs[4] = {};
    const f32x16 zero16 = {};

    for (int t = 0; t < 8; ++t) {
        if (t < 7) stage(t + 1);
        char* buf = base + (t & 1) * 8192;
#pragma unroll
        for (int h = 0; h < 2; ++h) {
            // QK^T (swapped): s = S^T[kv 32h..+32][q]; lane: q=lq, kv=32h+(r&3)+8(r>>2)+4hi
            const bf16x8 k0 = *reinterpret_cast<const bf16x8*>(buf + (h * 2 + 0) * 1024 + lane * 16);
            const bf16x8 k1 = *reinterpret_cast<const bf16x8*>(buf + (h * 2 + 1) * 1024 + lane * 16);
            __builtin_amdgcn_s_setprio(1);
            f32x16 s = __builtin_amdgcn_mfma_f32_32x32x16_bf16(k0, qf0, zero16, 0, 0, 0);
            s = __builtin_amdgcn_mfma_f32_32x32x16_bf16(k1, qf1, s, 0, 0, 0);
            __builtin_amdgcn_s_setprio(0);

            // zero-shift softmax, bare v_exp_f32 (inputs bounded: no denorm concerns)
#pragma unroll
            for (int r = 0; r < 16; ++r) s[r] = __builtin_amdgcn_exp2f(s[r]);
#pragma unroll
            for (int r = 0; r < 16; ++r) rs[r & 3] += s[r];

            // pack B-frag for PV via v_permlane32_swap_b32 (DST[63:32] <-> SRC[31:0])
#pragma unroll
            for (int cc = 0; cc < 2; ++cc) {
                const int b8 = cc * 8;
                uint32 u0 = pkbf(s[b8 + 0], s[b8 + 1]);
                uint32 u1 = pkbf(s[b8 + 2], s[b8 + 3]);
                uint32 u2 = pkbf(s[b8 + 4], s[b8 + 5]);
                uint32 u3 = pkbf(s[b8 + 6], s[b8 + 7]);
                asm volatile("v_permlane32_swap_b32 %0, %1" : "+v"(u0), "+v"(u2));
                asm volatile("v_permlane32_swap_b32 %0, %1" : "+v"(u1), "+v"(u3));
                union { uint32 u[4]; bf16x8 v; } pb;
                pb.u[0] = u0; pb.u[1] = u1; pb.u[2] = u2; pb.u[3] = u3;
                const bf16x8 vf = *reinterpret_cast<const bf16x8*>(buf + 4096 + (h * 2 + cc) * 1024 + lane * 16);
                __builtin_amdgcn_s_setprio(1);
                o = __builtin_amdgcn_mfma_f32_32x32x16_bf16(vf, pb.v, o, 0, 0, 0);
                __builtin_amdgcn_s_setprio(0);
            }
        }
        __syncthreads();
    }

    // row-sum over the hi pair (uniform across pair afterwards)
    float ls = (rs[0] + rs[1]) + (rs[2] + rs[3]);
    ls += __shfl_xor(ls, 32);

    // 4-way quarter merge through LDS (plain add: all quarters share zero shift)
    // per-strip region: Mo 16x64 f32 (4096B) + Ml 64 f32 (256B), 3 writers
    if (qt) {
        float* Mo = (float*)(smem + p * 13824 + (qt - 1) * 4608);
        float* Ml = (float*)(smem + p * 13824 + (qt - 1) * 4608 + 4096);
#pragma unroll
        for (int r = 0; r < 16; ++r) Mo[r * 64 + lane] = o[r];
        Ml[lane] = ls;
    }
    __syncthreads();
    if (!qt) {
        float lt = ls;
        f32x16 ot = o;
#pragma unroll
        for (int q = 0; q < 3; ++q) {
            const float* Mo = (const float*)(smem + p * 13824 + q * 4608);
            const float* Ml = (const float*)(smem + p * 13824 + q * 4608 + 4096);
            lt += Ml[lane];
#pragma unroll
            for (int r = 0; r < 16; ++r) ot[r] += Mo[r * 64 + lane];
        }
        const float inv = 1.f / lt;
        const int bb = head >> 4, hh = head & 15;
        const int row = bb * NSEQ + q0 + lq;
        const int colb = hh * CHD;
#pragma unroll
        for (int rq = 0; rq < 4; ++rq) {
            bf16x4 st;
#pragma unroll
            for (int ri = 0; ri < 4; ++ri)
                st[ri] = (bf16)(ot[rq * 4 + ri] * inv);
            *reinterpret_cast<bf16x4*>(outb + row * CDIM + colb + rq * 8 + hi * 4) = st;
        }
    }
}

// ---------------- launch ----------------
extern "C" void kernel_launch(void* const* d_in, const int* in_sizes, int n_in,
                              void* d_out, int out_size, void* d_ws, size_t ws_size,
                              hipStream_t stream) {
    const float* x      = (const float*)d_in[0];
    const float* w_qkv  = (const float*)d_in[1];
    const float* w_proj = (const float*)d_in[2];
    const float* b_proj = (const float*)d_in[3];
    float* out = (float*)d_out;

    char* ws = (char*)d_ws;
    bf16* xb  = (bf16*)(ws);                         // 4096x1024      (8 MiB)
    bf16* wqb = (bf16*)(ws + 8388608);               // 1536x1024      (3 MiB)
    bf16* wpb = (bf16*)(ws + 11534336);              // 1024x512       (1 MiB)
    bf16* qb  = (bf16*)(ws + 25165824);              // 32x2048x32     (4 MiB)
    bf16* kb  = (bf16*)(ws + 29360128);              // 32x2048x32     (4 MiB)
    bf16* vt  = (bf16*)(ws + 33554432);              // 32x32x2048     (4 MiB)
    bf16* ob  = (bf16*)(ws + 37748736);              // 4096x512       (4 MiB)

    cast_fused<<<(NX4 + NW4 + NP4) / 256, 256, 0, stream>>>(x, w_qkv, w_proj, xb, wqb, wpb);

    gemm_nt<DIM_, 1><<<dim3(32, 24), 256, 0, stream>>>(xb, wqb, qb, kb, vt, nullptr, nullptr);

    flash_kernel<<<512, 1024, 0, stream>>>(qb, kb, vt, ob);

    gemm_nt<CDIM, 2><<<dim3(32, 16), 256, 0, stream>>>(ob, wpb, nullptr, nullptr, nullptr, out, b_proj);
}

// Round 14
// 72.755 us; speedup vs baseline: 1.2239x; 1.2239x over previous
//
#include <hip/hip_runtime.h>

typedef __bf16 bf16;
typedef __bf16 bf16x8 __attribute__((ext_vector_type(8)));
typedef __bf16 bf16x4 __attribute__((ext_vector_type(4)));
typedef __bf16 bf16x2 __attribute__((ext_vector_type(2)));
typedef float  f32x4  __attribute__((ext_vector_type(4)));
typedef float  f32x16 __attribute__((ext_vector_type(16)));
typedef unsigned int uint32;

constexpr int DIM_  = 1024;
constexpr int NH    = 16;
constexpr int CHD   = 32;     // current head dim
constexpr int CDIM  = 512;    // NH * CHD
constexpr int CQ    = 1536;   // 3 * CDIM
constexpr int NSEQ  = 2048;
constexpr int M_    = 4096;   // B * N
constexpr float ATT_SCALE = 0.17677669529663687f; // (64^-0.5)/sqrt(0.5)
constexpr float QS_LOG2 = ATT_SCALE * 1.4426950408889634f; // fold log2(e): softmax in exp2 domain

__device__ inline void gload16(const bf16* g, bf16* l) {
    __builtin_amdgcn_global_load_lds((const __attribute__((address_space(1))) void*)g,
                                     (__attribute__((address_space(3))) void*)l, 16, 0, 0);
}

// ---------------- fused cast: x, w_qkv, w_proj slice -> bf16 (one launch) ----------------
constexpr int NX4 = M_ * DIM_ / 4;        // 1048576
constexpr int NW4 = CQ * DIM_ / 4;        // 393216
constexpr int NP4 = DIM_ * (CDIM / 4);    // 131072
__global__ void cast_fused(const float* __restrict__ x, const float* __restrict__ wq,
                           const float* __restrict__ wp, bf16* __restrict__ xb,
                           bf16* __restrict__ wqb, bf16* __restrict__ wpb) {
    int i = blockIdx.x * blockDim.x + threadIdx.x;   // exactly NX4+NW4+NP4 threads
    const float4* src;
    bf16x4* dst;
    if (i < NX4) {
        src = reinterpret_cast<const float4*>(x) + i;
        dst = reinterpret_cast<bf16x4*>(xb) + i;
    } else if (i < NX4 + NW4) {
        int j = i - NX4;
        src = reinterpret_cast<const float4*>(wq) + j;
        dst = reinterpret_cast<bf16x4*>(wqb) + j;
    } else {
        int j = i - (NX4 + NW4);
        int c = j >> 7, j4 = j & 127;
        src = reinterpret_cast<const float4*>(wp + c * DIM_) + j4;
        dst = reinterpret_cast<bf16x4*>(wpb + c * CDIM) + j4;
    }
    float4 v = *src;
    bf16x4 o = { (bf16)v.x, (bf16)v.y, (bf16)v.z, (bf16)v.w };
    *dst = o;
}

// ---------------- NT GEMM: C[m][n] = sum_k A[m][k] * B[n][k] ----------------
// 128x64 tile, 4 waves (2x2), wave tile 64x32, BK=32. 3-deep LDS ring, one barrier
// per K-step, counted vmcnt. Staging: coalesced row-major source (lane -> row lane>>2,
// 4x16B per row), linear LDS dest. (Frag-blob staging scatters the GLOBAL side and
// quadruples VMEM transactions -- measured 41us in R13. The ~4-way ds_read conflict
// of this layout is the cheaper side of the tradeoff.)
// MODE 1: qkv epilogue -> q/k via LDS-bounce (vector stores, q pre-scaled), v transposed
// MODE 2: proj epilogue -> f32 out + bias
template<int KDIM, int MODE>
__launch_bounds__(256)
__global__ void gemm_nt(const bf16* __restrict__ A, const bf16* __restrict__ Bm,
                        bf16* __restrict__ qbo, bf16* __restrict__ kbo, bf16* __restrict__ vto,
                        float* __restrict__ Cf, const float* __restrict__ bias) {
    __shared__ __align__(16) bf16 SMEM[18432];   // As ring 12288 | Bs ring 6144; bounce reuse
    bf16* As = SMEM;             // 3 bufs x 4096 elems (128x32)
    bf16* Bs = SMEM + 12288;     // 3 bufs x 2048 elems (64x32)
    const int tid = threadIdx.x;
    const int w = tid >> 6, lane = tid & 63;
    const int m0 = blockIdx.x * 128, n0 = blockIdx.y * 64;
    const int wr = (w >> 1) * 64, wc = (w & 1) * 32;
    const int lrow = lane >> 2, lk = (lane & 3) * 8;
    const int cl = lane & 15, gk8 = (lane >> 4) * 8;

    const bf16* ga = A  + (m0 + w * 16 + lrow) * KDIM + lk;
    const bf16* gb = Bm + (n0 + w * 16 + lrow) * KDIM + lk;

    constexpr int KT = KDIM / 32;

    auto stage = [&](int kt, int b) {
        gload16(ga + kt * 32,             As + b * 4096 + w * 512);
        gload16(ga + kt * 32 + 64 * KDIM, As + b * 4096 + 2048 + w * 512);
        gload16(gb + kt * 32,             Bs + b * 2048 + w * 512);
    };
    stage(0, 0);
    stage(1, 1);

    f32x4 acc[4][2] = {};

    for (int kt = 0; kt < KT; ++kt) {
        if (kt < KT - 1) asm volatile("s_waitcnt vmcnt(3)" ::: "memory");
        else             asm volatile("s_waitcnt vmcnt(0)" ::: "memory");
        __builtin_amdgcn_s_barrier();
        __builtin_amdgcn_sched_barrier(0);
        if (kt + 2 < KT) stage(kt + 2, (kt + 2) % 3);

        const bf16* as = As + (kt % 3) * 4096;
        const bf16* bs = Bs + (kt % 3) * 2048;
        bf16x8 af[4], bfr[2];
#pragma unroll
        for (int i = 0; i < 4; ++i)
            af[i]  = *reinterpret_cast<const bf16x8*>(as + (wr + i * 16 + cl) * 32 + gk8);
#pragma unroll
        for (int j = 0; j < 2; ++j)
            bfr[j] = *reinterpret_cast<const bf16x8*>(bs + (wc + j * 16 + cl) * 32 + gk8);
#pragma unroll
        for (int i = 0; i < 4; ++i)
#pragma unroll
            for (int j = 0; j < 2; ++j)
                acc[i][j] = __builtin_amdgcn_mfma_f32_16x16x32_bf16(af[i], bfr[j], acc[i][j], 0, 0, 0);
    }

    const int rg = (lane >> 4) * 4;   // D layout: row=(l>>4)*4+r, col=l&15
    if constexpr (MODE == 2) {
#pragma unroll
        for (int i = 0; i < 4; ++i)
#pragma unroll
            for (int j = 0; j < 2; ++j) {
                const int row = m0 + wr + i * 16 + rg;
                const int col = n0 + wc + j * 16 + cl;
                const float bv = bias[col];
#pragma unroll
                for (int r = 0; r < 4; ++r)
                    Cf[(row + r) * DIM_ + col] = acc[i][j][r] + bv;
            }
    } else {
        const int sec = n0 >> 9;   // block-uniform: 0=q 1=k 2=v
        if (sec == 2) {
#pragma unroll
            for (int i = 0; i < 4; ++i)
#pragma unroll
                for (int j = 0; j < 2; ++j) {
                    const int row = m0 + wr + i * 16 + rg;
                    const int col = n0 + wc + j * 16 + cl;
                    const int rem = col & 511;
                    const int h = rem >> 5, d = rem & 31;
                    const int bb = row >> 11, pos = row & 2047;
                    const int bh = bb * NH + h;
                    bf16x4 st;
#pragma unroll
                    for (int r = 0; r < 4; ++r) st[r] = (bf16)acc[i][j][r];
                    *reinterpret_cast<bf16x4*>(vto + (bh * CHD + d) * NSEQ + pos) = st;
                }
        } else {
            // bounce through LDS -> coalesced b128 stores
            const float sc = sec ? 1.0f : QS_LOG2;
            __syncthreads();   // done reading As/Bs
#pragma unroll
            for (int i = 0; i < 4; ++i)
#pragma unroll
                for (int j = 0; j < 2; ++j)
#pragma unroll
                    for (int r = 0; r < 4; ++r)
                        SMEM[(wr + i * 16 + rg + r) * 72 + wc + j * 16 + cl] =
                            (bf16)(acc[i][j][r] * sc);
            __syncthreads();
            const int row = tid >> 1, ch = (tid & 1) * 32;
            const int m = m0 + row, bb = m >> 11, pos = m & 2047;
            const int col0 = n0 + ch;
            const int h = (col0 & 511) >> 5;
            bf16* dst = (sec ? kbo : qbo) + ((bb * NH + h) * NSEQ + pos) * CHD;
#pragma unroll
            for (int v4 = 0; v4 < 4; ++v4)
                *reinterpret_cast<bf16x8*>(dst + v4 * 8) =
                    *reinterpret_cast<const bf16x8*>(SMEM + row * 72 + ch + v4 * 8);
        }
    }
}

// pack two f32 -> dword of two bf16 (v_cvt_pk_bf16_f32)
__device__ inline uint32 pkbf(float lo, float hi) {
    bf16x2 t = { (bf16)lo, (bf16)hi };
    return __builtin_bit_cast(uint32, t);
}

// ---------------- flash attention v9: 16-wave blocks, kv-quarters, 8 waves/SIMD ----------------
// Grid 512 blocks x 1024 thr (16 waves): strip p = w&3 (32 q-rows each), kv-quarter
// qt = w>>2 (512 kv each). Per wave: 8 KV tiles of 64, two 32-kv h-blocks per tile:
// QK(2 MFMA, swapped) -> p=exp2(s) (bare v_exp_f32, zero-shift softmax) -> permlane
// pack -> PV (one accumulator). K/V double-buffered per quarter in LDS (64KB total)
// via global_load_lds frag-blobs. Occupancy: 2 blocks/CU exact = 8 waves/SIMD.
// 4-way quarter merge via LDS at the end.
__launch_bounds__(1024, 8)
__global__ void flash_kernel(const bf16* __restrict__ qb, const bf16* __restrict__ kb,
                             const bf16* __restrict__ vt, bf16* __restrict__ outb) {
    __shared__ __align__(16) char smem[65536];  // [quarter][par][K 4KB | V 4KB]; merge reuse
    const int tid = threadIdx.x;
    const int w = tid >> 6, lane = tid & 63;
    const int lq = lane & 31, hi = lane >> 5;
    const int p = w & 3, qt = w >> 2;

    const int blin = blockIdx.x;                 // XCD swizzle: 4 heads per XCD
    const int xcd = blin & 7, within = blin >> 3;
    const int head = xcd * 4 + (within >> 4);
    const int qblk = within & 15;
    const int q0 = qblk * 128 + p * 32;

    const bf16* Q = qb + head * (NSEQ * CHD);
    const bf16* K = kb + head * (NSEQ * CHD);
    const bf16* V = vt + head * (CHD * NSEQ);    // V^T: [d][pos]

    // Q B-fragments (kc=0,1): lane -> Q[q0+lq][16*kc + 8*hi + j]
    const bf16x8 qf0 = *reinterpret_cast<const bf16x8*>(Q + (q0 + lq) * CHD + hi * 8);
    const bf16x8 qf1 = *reinterpret_cast<const bf16x8*>(Q + (q0 + lq) * CHD + 16 + hi * 8);

    char* base = smem + qt * 16384;
    const int kvbeg = qt * 512;                  // this quarter's kv range
    // staging: strip-wave p stages K-blob p (sh=p>>1, skc=p&1) and V-blob p of its quarter
    const int sh = p >> 1, skc = p & 1;
    const bf16* srcK = K + (kvbeg + sh * 32 + lq) * CHD + skc * 16 + hi * 8;
    const bf16* srcV = V + lq * NSEQ + kvbeg + p * 16 + hi * 8;

    auto stage = [&](int t) {
        char* b = base + (t & 1) * 8192;
        gload16(srcK + t * 64 * CHD, (bf16*)(b + p * 1024));
        gload16(srcV + t * 64,       (bf16*)(b + 4096 + p * 1024));
    };
    stage(0);
    __syncthreads();

    f32x16 o = {};
    float rs[4] = {};
    const f32x16 zero16 = {};

    for (int t = 0; t < 8; ++t) {
        if (t < 7) stage(t + 1);
        char* buf = base + (t & 1) * 8192;
#pragma unroll
        for (int h = 0; h < 2; ++h) {
            // QK^T (swapped): s = S^T[kv 32h..+32][q]; lane: q=lq, kv=32h+(r&3)+8(r>>2)+4hi
            const bf16x8 k0 = *reinterpret_cast<const bf16x8*>(buf + (h * 2 + 0) * 1024 + lane * 16);
            const bf16x8 k1 = *reinterpret_cast<const bf16x8*>(buf + (h * 2 + 1) * 1024 + lane * 16);
            __builtin_amdgcn_s_setprio(1);
            f32x16 s = __builtin_amdgcn_mfma_f32_32x32x16_bf16(k0, qf0, zero16, 0, 0, 0);
            s = __builtin_amdgcn_mfma_f32_32x32x16_bf16(k1, qf1, s, 0, 0, 0);
            __builtin_amdgcn_s_setprio(0);

            // zero-shift softmax, bare v_exp_f32 (inputs bounded: no denorm concerns)
#pragma unroll
            for (int r = 0; r < 16; ++r) s[r] = __builtin_amdgcn_exp2f(s[r]);
#pragma unroll
            for (int r = 0; r < 16; ++r) rs[r & 3] += s[r];

            // pack B-frag for PV via v_permlane32_swap_b32 (DST[63:32] <-> SRC[31:0])
#pragma unroll
            for (int cc = 0; cc < 2; ++cc) {
                const int b8 = cc * 8;
                uint32 u0 = pkbf(s[b8 + 0], s[b8 + 1]);
                uint32 u1 = pkbf(s[b8 + 2], s[b8 + 3]);
                uint32 u2 = pkbf(s[b8 + 4], s[b8 + 5]);
                uint32 u3 = pkbf(s[b8 + 6], s[b8 + 7]);
                asm volatile("v_permlane32_swap_b32 %0, %1" : "+v"(u0), "+v"(u2));
                asm volatile("v_permlane32_swap_b32 %0, %1" : "+v"(u1), "+v"(u3));
                union { uint32 u[4]; bf16x8 v; } pb;
                pb.u[0] = u0; pb.u[1] = u1; pb.u[2] = u2; pb.u[3] = u3;
                const bf16x8 vf = *reinterpret_cast<const bf16x8*>(buf + 4096 + (h * 2 + cc) * 1024 + lane * 16);
                __builtin_amdgcn_s_setprio(1);
                o = __builtin_amdgcn_mfma_f32_32x32x16_bf16(vf, pb.v, o, 0, 0, 0);
                __builtin_amdgcn_s_setprio(0);
            }
        }
        __syncthreads();
    }

    // row-sum over the hi pair (uniform across pair afterwards)
    float ls = (rs[0] + rs[1]) + (rs[2] + rs[3]);
    ls += __shfl_xor(ls, 32);

    // 4-way quarter merge through LDS (plain add: all quarters share zero shift)
    // per-strip region: Mo 16x64 f32 (4096B) + Ml 64 f32 (256B), 3 writers
    if (qt) {
        float* Mo = (float*)(smem + p * 13824 + (qt - 1) * 4608);
        float* Ml = (float*)(smem + p * 13824 + (qt - 1) * 4608 + 4096);
#pragma unroll
        for (int r = 0; r < 16; ++r) Mo[r * 64 + lane] = o[r];
        Ml[lane] = ls;
    }
    __syncthreads();
    if (!qt) {
        float lt = ls;
        f32x16 ot = o;
#pragma unroll
        for (int q = 0; q < 3; ++q) {
            const float* Mo = (const float*)(smem + p * 13824 + q * 4608);
            const float* Ml = (const float*)(smem + p * 13824 + q * 4608 + 4096);
            lt += Ml[lane];
#pragma unroll
            for (int r = 0; r < 16; ++r) ot[r] += Mo[r * 64 + lane];
        }
        const float inv = 1.f / lt;
        const int bb = head >> 4, hh = head & 15;
        const int row = bb * NSEQ + q0 + lq;
        const int colb = hh * CHD;
#pragma unroll
        for (int rq = 0; rq < 4; ++rq) {
            bf16x4 st;
#pragma unroll
            for (int ri = 0; ri < 4; ++ri)
                st[ri] = (bf16)(ot[rq * 4 + ri] * inv);
            *reinterpret_cast<bf16x4*>(outb + row * CDIM + colb + rq * 8 + hi * 4) = st;
        }
    }
}

// ---------------- launch ----------------
extern "C" void kernel_launch(void* const* d_in, const int* in_sizes, int n_in,
                              void* d_out, int out_size, void* d_ws, size_t ws_size,
                              hipStream_t stream) {
    const float* x      = (const float*)d_in[0];
    const float* w_qkv  = (const float*)d_in[1];
    const float* w_proj = (const float*)d_in[2];
    const float* b_proj = (const float*)d_in[3];
    float* out = (float*)d_out;

    char* ws = (char*)d_ws;
    bf16* xb  = (bf16*)(ws);                         // 4096x1024      (8 MiB)
    bf16* wqb = (bf16*)(ws + 8388608);               // 1536x1024      (3 MiB)
    bf16* wpb = (bf16*)(ws + 11534336);              // 1024x512       (1 MiB)
    bf16* qb  = (bf16*)(ws + 25165824);              // 32x2048x32     (4 MiB)
    bf16* kb  = (bf16*)(ws + 29360128);              // 32x2048x32     (4 MiB)
    bf16* vt  = (bf16*)(ws + 33554432);              // 32x32x2048     (4 MiB)
    bf16* ob  = (bf16*)(ws + 37748736);              // 4096x512       (4 MiB)

    cast_fused<<<(NX4 + NW4 + NP4) / 256, 256, 0, stream>>>(x, w_qkv, w_proj, xb, wqb, wpb);

    gemm_nt<DIM_, 1><<<dim3(32, 24), 256, 0, stream>>>(xb, wqb, qb, kb, vt, nullptr, nullptr);

    flash_kernel<<<512, 1024, 0, stream>>>(qb, kb, vt, ob);

    gemm_nt<CDIM, 2><<<dim3(32, 16), 256, 0, stream>>>(ob, wpb, nullptr, nullptr, nullptr, out, b_proj);
}

// Round 15
// 68.168 us; speedup vs baseline: 1.3063x; 1.0673x over previous
//
#include <hip/hip_runtime.h>

typedef __bf16 bf16;
typedef __bf16 bf16x8 __attribute__((ext_vector_type(8)));
typedef __bf16 bf16x4 __attribute__((ext_vector_type(4)));
typedef __bf16 bf16x2 __attribute__((ext_vector_type(2)));
typedef float  f32x4  __attribute__((ext_vector_type(4)));
typedef float  f32x16 __attribute__((ext_vector_type(16)));
typedef unsigned int uint32;

constexpr int DIM_  = 1024;
constexpr int NH    = 16;
constexpr int CHD   = 32;     // current head dim
constexpr int CDIM  = 512;    // NH * CHD
constexpr int CQ    = 1536;   // 3 * CDIM
constexpr int NSEQ  = 2048;
constexpr int M_    = 4096;   // B * N
constexpr float ATT_SCALE = 0.17677669529663687f; // (64^-0.5)/sqrt(0.5)
constexpr float QS_LOG2 = ATT_SCALE * 1.4426950408889634f; // fold log2(e): softmax in exp2 domain

__device__ inline void gload16(const bf16* g, bf16* l) {
    __builtin_amdgcn_global_load_lds((const __attribute__((address_space(1))) void*)g,
                                     (__attribute__((address_space(3))) void*)l, 16, 0, 0);
}

// ---------------- fused cast: x, w_qkv, w_proj slice -> bf16 (one launch) ----------------
constexpr int NX4 = M_ * DIM_ / 4;        // 1048576
constexpr int NW4 = CQ * DIM_ / 4;        // 393216
constexpr int NP4 = DIM_ * (CDIM / 4);    // 131072
__global__ void cast_fused(const float* __restrict__ x, const float* __restrict__ wq,
                           const float* __restrict__ wp, bf16* __restrict__ xb,
                           bf16* __restrict__ wqb, bf16* __restrict__ wpb) {
    int i = blockIdx.x * blockDim.x + threadIdx.x;   // exactly NX4+NW4+NP4 threads
    const float4* src;
    bf16x4* dst;
    if (i < NX4) {
        src = reinterpret_cast<const float4*>(x) + i;
        dst = reinterpret_cast<bf16x4*>(xb) + i;
    } else if (i < NX4 + NW4) {
        int j = i - NX4;
        src = reinterpret_cast<const float4*>(wq) + j;
        dst = reinterpret_cast<bf16x4*>(wqb) + j;
    } else {
        int j = i - (NX4 + NW4);
        int c = j >> 7, j4 = j & 127;
        src = reinterpret_cast<const float4*>(wp + c * DIM_) + j4;
        dst = reinterpret_cast<bf16x4*>(wpb + c * CDIM) + j4;
    }
    float4 v = *src;
    bf16x4 o = { (bf16)v.x, (bf16)v.y, (bf16)v.z, (bf16)v.w };
    *dst = o;
}

// ---------------- NT GEMM: C[m][n] = sum_k A[m][k] * B[n][k] ----------------
// 128x64 tile, 4 waves (2x2), BK=64 (16/8 K-steps): 16 MFMA per barrier.
// LDS layout XOR-swizzled on 16B chunks: stored chunk' = chunk ^ (row&7).
// Staging pre-swizzles the GLOBAL source per-lane -- the permutation stays inside
// each row's 128B segment, so coalescing is preserved (R13's mistake avoided).
// Fragment ds_reads then land 2-way max (free). Double-buffered, v8-style loop.
// MODE 1: qkv epilogue -> q/k via LDS-bounce (vector stores, q pre-scaled), v transposed
// MODE 2: proj epilogue -> f32 out + bias
template<int KDIM, int MODE>
__launch_bounds__(256)
__global__ void gemm_nt(const bf16* __restrict__ A, const bf16* __restrict__ Bm,
                        bf16* __restrict__ qbo, bf16* __restrict__ kbo, bf16* __restrict__ vto,
                        float* __restrict__ Cf, const float* __restrict__ bias) {
    __shared__ __align__(16) bf16 SMEM[24576];   // As 2x8192 | Bs 2x4096 (48KB); bounce reuse
    bf16* As = SMEM;             // [buf][row 0..127][chunk' 0..7]  (chunk = 8 bf16 = 16B)
    bf16* Bs = SMEM + 16384;     // [buf][row 0..63][chunk' 0..7]
    const int tid = threadIdx.x;
    const int w = tid >> 6, lane = tid & 63;
    const int m0 = blockIdx.x * 128, n0 = blockIdx.y * 64;
    const int wr = (w >> 1) * 64, wc = (w & 1) * 32;
    const int cl = lane & 15, hi = lane >> 4;    // fragment row / k-group
    const int swz = cl & 7;                      // read-side XOR

    // staging source: lane l -> row (c*8 + l>>3), global chunk (l&7)^(l>>3)  [row&7 == l>>3]
    const int srow = lane >> 3, schk = (lane & 7) ^ (lane >> 3);
    const bf16* gaA = A  + (m0 + srow) * KDIM + schk * 8;
    const bf16* gbB = Bm + (n0 + srow) * KDIM + schk * 8;

    constexpr int KT = KDIM / 64;

    auto stage = [&](int kt, int b) {
#pragma unroll
        for (int i = 0; i < 4; ++i)   // A chunks: wave w covers c = 4w..4w+3 (rows c*8..c*8+7)
            gload16(gaA + (w * 4 + i) * 8 * KDIM + kt * 64, As + b * 8192 + (w * 4 + i) * 512);
#pragma unroll
        for (int i = 0; i < 2; ++i)   // B chunks: wave w covers c = 2w..2w+1
            gload16(gbB + (w * 2 + i) * 8 * KDIM + kt * 64, Bs + b * 4096 + (w * 2 + i) * 512);
    };
    stage(0, 0);
    __syncthreads();

    f32x4 acc[4][2] = {};

    for (int kt = 0; kt < KT; ++kt) {
        if (kt + 1 < KT) stage(kt + 1, (kt + 1) & 1);
        const bf16* as = As + (kt & 1) * 8192;
        const bf16* bs = Bs + (kt & 1) * 4096;
#pragma unroll
        for (int kh = 0; kh < 2; ++kh) {
            const int ck = ((kh * 4 + hi) ^ swz) * 8;   // swizzled chunk offset (elems)
            bf16x8 af[4], bfr[2];
#pragma unroll
            for (int i = 0; i < 4; ++i)
                af[i]  = *reinterpret_cast<const bf16x8*>(as + (wr + i * 16 + cl) * 64 + ck);
#pragma unroll
            for (int j = 0; j < 2; ++j)
                bfr[j] = *reinterpret_cast<const bf16x8*>(bs + (wc + j * 16 + cl) * 64 + ck);
#pragma unroll
            for (int i = 0; i < 4; ++i)
#pragma unroll
                for (int j = 0; j < 2; ++j)
                    acc[i][j] = __builtin_amdgcn_mfma_f32_16x16x32_bf16(af[i], bfr[j], acc[i][j], 0, 0, 0);
        }
        __syncthreads();
    }

    const int rg = hi * 4;   // D layout: row=(l>>4)*4+r, col=l&15
    if constexpr (MODE == 2) {
#pragma unroll
        for (int i = 0; i < 4; ++i)
#pragma unroll
            for (int j = 0; j < 2; ++j) {
                const int row = m0 + wr + i * 16 + rg;
                const int col = n0 + wc + j * 16 + cl;
                const float bv = bias[col];
#pragma unroll
                for (int r = 0; r < 4; ++r)
                    Cf[(row + r) * DIM_ + col] = acc[i][j][r] + bv;
            }
    } else {
        const int sec = n0 >> 9;   // block-uniform: 0=q 1=k 2=v
        if (sec == 2) {
#pragma unroll
            for (int i = 0; i < 4; ++i)
#pragma unroll
                for (int j = 0; j < 2; ++j) {
                    const int row = m0 + wr + i * 16 + rg;
                    const int col = n0 + wc + j * 16 + cl;
                    const int rem = col & 511;
                    const int h = rem >> 5, d = rem & 31;
                    const int bb = row >> 11, pos = row & 2047;
                    const int bh = bb * NH + h;
                    bf16x4 st;
#pragma unroll
                    for (int r = 0; r < 4; ++r) st[r] = (bf16)acc[i][j][r];
                    *reinterpret_cast<bf16x4*>(vto + (bh * CHD + d) * NSEQ + pos) = st;
                }
        } else {
            // bounce through LDS -> coalesced b128 stores
            const float sc = sec ? 1.0f : QS_LOG2;
            __syncthreads();   // done reading As/Bs
#pragma unroll
            for (int i = 0; i < 4; ++i)
#pragma unroll
                for (int j = 0; j < 2; ++j)
#pragma unroll
                    for (int r = 0; r < 4; ++r)
                        SMEM[(wr + i * 16 + rg + r) * 72 + wc + j * 16 + cl] =
                            (bf16)(acc[i][j][r] * sc);
            __syncthreads();
            const int row = tid >> 1, ch = (tid & 1) * 32;
            const int m = m0 + row, bb = m >> 11, pos = m & 2047;
            const int col0 = n0 + ch;
            const int h = (col0 & 511) >> 5;
            bf16* dst = (sec ? kbo : qbo) + ((bb * NH + h) * NSEQ + pos) * CHD;
#pragma unroll
            for (int v4 = 0; v4 < 4; ++v4)
                *reinterpret_cast<bf16x8*>(dst + v4 * 8) =
                    *reinterpret_cast<const bf16x8*>(SMEM + row * 72 + ch + v4 * 8);
        }
    }
}

// pack two f32 -> dword of two bf16 (v_cvt_pk_bf16_f32)
__device__ inline uint32 pkbf(float lo, float hi) {
    bf16x2 t = { (bf16)lo, (bf16)hi };
    return __builtin_bit_cast(uint32, t);
}

// ---------------- flash attention v9: 16-wave blocks, kv-quarters (unchanged from R14) ----------------
__launch_bounds__(1024, 8)
__global__ void flash_kernel(const bf16* __restrict__ qb, const bf16* __restrict__ kb,
                             const bf16* __restrict__ vt, bf16* __restrict__ outb) {
    __shared__ __align__(16) char smem[65536];  // [quarter][par][K 4KB | V 4KB]; merge reuse
    const int tid = threadIdx.x;
    const int w = tid >> 6, lane = tid & 63;
    const int lq = lane & 31, hi = lane >> 5;
    const int p = w & 3, qt = w >> 2;

    const int blin = blockIdx.x;                 // XCD swizzle: 4 heads per XCD
    const int xcd = blin & 7, within = blin >> 3;
    const int head = xcd * 4 + (within >> 4);
    const int qblk = within & 15;
    const int q0 = qblk * 128 + p * 32;

    const bf16* Q = qb + head * (NSEQ * CHD);
    const bf16* K = kb + head * (NSEQ * CHD);
    const bf16* V = vt + head * (CHD * NSEQ);    // V^T: [d][pos]

    // Q B-fragments (kc=0,1): lane -> Q[q0+lq][16*kc + 8*hi + j]
    const bf16x8 qf0 = *reinterpret_cast<const bf16x8*>(Q + (q0 + lq) * CHD + hi * 8);
    const bf16x8 qf1 = *reinterpret_cast<const bf16x8*>(Q + (q0 + lq) * CHD + 16 + hi * 8);

    char* base = smem + qt * 16384;
    const int kvbeg = qt * 512;                  // this quarter's kv range
    const int sh = p >> 1, skc = p & 1;
    const bf16* srcK = K + (kvbeg + sh * 32 + lq) * CHD + skc * 16 + hi * 8;
    const bf16* srcV = V + lq * NSEQ + kvbeg + p * 16 + hi * 8;

    auto stage = [&](int t) {
        char* b = base + (t & 1) * 8192;
        gload16(srcK + t * 64 * CHD, (bf16*)(b + p * 1024));
        gload16(srcV + t * 64,       (bf16*)(b + 4096 + p * 1024));
    };
    stage(0);
    __syncthreads();

    f32x16 o = {};
    float rs[4] = {};
    const f32x16 zero16 = {};

    for (int t = 0; t < 8; ++t) {
        if (t < 7) stage(t + 1);
        char* buf = base + (t & 1) * 8192;
#pragma unroll
        for (int h = 0; h < 2; ++h) {
            // QK^T (swapped): s = S^T[kv 32h..+32][q]; lane: q=lq, kv=32h+(r&3)+8(r>>2)+4hi
            const bf16x8 k0 = *reinterpret_cast<const bf16x8*>(buf + (h * 2 + 0) * 1024 + lane * 16);
            const bf16x8 k1 = *reinterpret_cast<const bf16x8*>(buf + (h * 2 + 1) * 1024 + lane * 16);
            __builtin_amdgcn_s_setprio(1);
            f32x16 s = __builtin_amdgcn_mfma_f32_32x32x16_bf16(k0, qf0, zero16, 0, 0, 0);
            s = __builtin_amdgcn_mfma_f32_32x32x16_bf16(k1, qf1, s, 0, 0, 0);
            __builtin_amdgcn_s_setprio(0);

            // zero-shift softmax, bare v_exp_f32 (inputs bounded: no denorm concerns)
#pragma unroll
            for (int r = 0; r < 16; ++r) s[r] = __builtin_amdgcn_exp2f(s[r]);
#pragma unroll
            for (int r = 0; r < 16; ++r) rs[r & 3] += s[r];

            // pack B-frag for PV via v_permlane32_swap_b32 (DST[63:32] <-> SRC[31:0])
#pragma unroll
            for (int cc = 0; cc < 2; ++cc) {
                const int b8 = cc * 8;
                uint32 u0 = pkbf(s[b8 + 0], s[b8 + 1]);
                uint32 u1 = pkbf(s[b8 + 2], s[b8 + 3]);
                uint32 u2 = pkbf(s[b8 + 4], s[b8 + 5]);
                uint32 u3 = pkbf(s[b8 + 6], s[b8 + 7]);
                asm volatile("v_permlane32_swap_b32 %0, %1" : "+v"(u0), "+v"(u2));
                asm volatile("v_permlane32_swap_b32 %0, %1" : "+v"(u1), "+v"(u3));
                union { uint32 u[4]; bf16x8 v; } pb;
                pb.u[0] = u0; pb.u[1] = u1; pb.u[2] = u2; pb.u[3] = u3;
                const bf16x8 vf = *reinterpret_cast<const bf16x8*>(buf + 4096 + (h * 2 + cc) * 1024 + lane * 16);
                __builtin_amdgcn_s_setprio(1);
                o = __builtin_amdgcn_mfma_f32_32x32x16_bf16(vf, pb.v, o, 0, 0, 0);
                __builtin_amdgcn_s_setprio(0);
            }
        }
        __syncthreads();
    }

    // row-sum over the hi pair (uniform across pair afterwards)
    float ls = (rs[0] + rs[1]) + (rs[2] + rs[3]);
    ls += __shfl_xor(ls, 32);

    // 4-way quarter merge through LDS (plain add: all quarters share zero shift)
    if (qt) {
        float* Mo = (float*)(smem + p * 13824 + (qt - 1) * 4608);
        float* Ml = (float*)(smem + p * 13824 + (qt - 1) * 4608 + 4096);
#pragma unroll
        for (int r = 0; r < 16; ++r) Mo[r * 64 + lane] = o[r];
        Ml[lane] = ls;
    }
    __syncthreads();
    if (!qt) {
        float lt = ls;
        f32x16 ot = o;
#pragma unroll
        for (int q = 0; q < 3; ++q) {
            const float* Mo = (const float*)(smem + p * 13824 + q * 4608);
            const float* Ml = (const float*)(smem + p * 13824 + q * 4608 + 4096);
            lt += Ml[lane];
#pragma unroll
            for (int r = 0; r < 16; ++r) ot[r] += Mo[r * 64 + lane];
        }
        const float inv = 1.f / lt;
        const int bb = head >> 4, hh = head & 15;
        const int row = bb * NSEQ + q0 + lq;
        const int colb = hh * CHD;
#pragma unroll
        for (int rq = 0; rq < 4; ++rq) {
            bf16x4 st;
#pragma unroll
            for (int ri = 0; ri < 4; ++ri)
                st[ri] = (bf16)(ot[rq * 4 + ri] * inv);
            *reinterpret_cast<bf16x4*>(outb + row * CDIM + colb + rq * 8 + hi * 4) = st;
        }
    }
}

// ---------------- launch ----------------
extern "C" void kernel_launch(void* const* d_in, const int* in_sizes, int n_in,
                              void* d_out, int out_size, void* d_ws, size_t ws_size,
                              hipStream_t stream) {
    const float* x      = (const float*)d_in[0];
    const float* w_qkv  = (const float*)d_in[1];
    const float* w_proj = (const float*)d_in[2];
    const float* b_proj = (const float*)d_in[3];
    float* out = (float*)d_out;

    char* ws = (char*)d_ws;
    bf16* xb  = (bf16*)(ws);                         // 4096x1024      (8 MiB)
    bf16* wqb = (bf16*)(ws + 8388608);               // 1536x1024      (3 MiB)
    bf16* wpb = (bf16*)(ws + 11534336);              // 1024x512       (1 MiB)
    bf16* qb  = (bf16*)(ws + 25165824);              // 32x2048x32     (4 MiB)
    bf16* kb  = (bf16*)(ws + 29360128);              // 32x2048x32     (4 MiB)
    bf16* vt  = (bf16*)(ws + 33554432);              // 32x32x2048     (4 MiB)
    bf16* ob  = (bf16*)(ws + 37748736);              // 4096x512       (4 MiB)

    cast_fused<<<(NX4 + NW4 + NP4) / 256, 256, 0, stream>>>(x, w_qkv, w_proj, xb, wqb, wpb);

    gemm_nt<DIM_, 1><<<dim3(32, 24), 256, 0, stream>>>(xb, wqb, qb, kb, vt, nullptr, nullptr);

    flash_kernel<<<512, 1024, 0, stream>>>(qb, kb, vt, ob);

    gemm_nt<CDIM, 2><<<dim3(32, 16), 256, 0, stream>>>(ob, wpb, nullptr, nullptr, nullptr, out, b_proj);
}